// Round 10
// baseline (140.871 us; speedup 1.0000x reference)
//
#include <hip/hip_runtime.h>

#define NBINS 229
#define OUTF  88
#define MODEL 128
#define WSZ   30
#define WIN   61
#define TLEN  1024
#define BT    4096

#define NC1 648      // gemm1 real cols
#define NP1 704      // gemm1 padded cols (11*64)
#define KP1 256      // gemm1 padded K (8*32); real 229
#define NC2 216      // gemm2 real cols
#define KP2 192      // gemm2 padded K (6*32); real 176

typedef short bf16x8 __attribute__((ext_vector_type(8)));
typedef float f32x4 __attribute__((ext_vector_type(4)));
typedef unsigned short ushort_t;

__device__ __forceinline__ float sigmoid_f(float x) {
    return __builtin_amdgcn_rcpf(1.f + __expf(-x));
}
__device__ __forceinline__ ushort_t f2bf(float f) {
    unsigned u = __float_as_uint(f);
    return (ushort_t)((u + 0x7fffu + ((u >> 16) & 1u)) >> 16);
}

// ---------------------------------------------------------------------------
// prep: build bf16 GEMM operands + fp32 biases + sv sums + xB k-pad zeros.
// B1b[n][k] (n-major, 704x256) column map (n):
//   [  0, 88) Wf[k][n]          [ 88,216) Wao[k][n-88]
//   [216,344) Wao[k+229][n-216] [344,472) Wac[k+176][n-344]
//   [472,560) Wl1[k][n-472]     [560,648) Wlc[k+176][n-560]
// B2b[n][k] (256x192): [0,128) Wac[k][n]; [128,216) Wlc[k][n-128]; pad 0
// specB[4096][256] bf16 row-major (k>=229 zero)
// xB[4096][192] bf16: cols 176..191 zeroed here
// bias1: [0,88)=bf, [88,216)=bao, else 0 ; bias2: [0,128)=bac, else 0
// sv[0]=sum(vo), sv[1]=sum(vc)
// ---------------------------------------------------------------------------
#define PREP_BLOCKS 2181

__global__ __launch_bounds__(256) void prep_kernel(
    const float* __restrict__ Wf,  const float* __restrict__ bfr,
    const float* __restrict__ Wao, const float* __restrict__ bao,
    const float* __restrict__ Wl1,
    const float* __restrict__ Wac, const float* __restrict__ bac,
    const float* __restrict__ Wlc,
    const float* __restrict__ spec,
    const float* __restrict__ vo, const float* __restrict__ vc,
    ushort_t* __restrict__ B1b, ushort_t* __restrict__ B2b,
    ushort_t* __restrict__ specB, ushort_t* __restrict__ xB,
    float* __restrict__ bias1, float* __restrict__ bias2,
    float* __restrict__ sv)
{
    __shared__ float red[4];
    const int b = blockIdx.x;
    if (b < 704) {                                  // B1b
        int idx = b * 256 + threadIdx.x;
        int n = idx >> 8, k = idx & 255;
        float v = 0.f;
        if (k < NBINS && n < NC1) {
            if (n < 88)       v = Wf[k * 88 + n];
            else if (n < 216) v = Wao[k * MODEL + (n - 88)];
            else if (n < 344) v = Wao[(k + NBINS) * MODEL + (n - 216)];
            else if (n < 472) v = Wac[(k + 176) * MODEL + (n - 344)];
            else if (n < 560) v = Wl1[k * 88 + (n - 472)];
            else              v = Wlc[(k + 176) * 88 + (n - 560)];
        }
        B1b[idx] = f2bf(v);
    } else if (b < 896) {                           // B2b
        int idx = (b - 704) * 256 + threadIdx.x;
        int n = idx / 192, k = idx - n * 192;
        float v = 0.f;
        if (k < 176 && n < NC2)
            v = (n < 128) ? Wac[k * MODEL + n] : Wlc[k * 88 + (n - 128)];
        B2b[idx] = f2bf(v);
    } else if (b < 1920) {                          // specB, 4 elems/thread
        int idx = (b - 896) * 256 + threadIdx.x;
        int r = idx >> 6, k4 = (idx & 63) * 4;
        const float* sp = spec + (size_t)r * NBINS;
        ushort4 o;
        o.x = (k4 + 0 < NBINS) ? f2bf(sp[k4 + 0]) : (ushort_t)0;
        o.y = (k4 + 1 < NBINS) ? f2bf(sp[k4 + 1]) : (ushort_t)0;
        o.z = (k4 + 2 < NBINS) ? f2bf(sp[k4 + 2]) : (ushort_t)0;
        o.w = (k4 + 3 < NBINS) ? f2bf(sp[k4 + 3]) : (ushort_t)0;
        *(ushort4*)&specB[(size_t)r * 256 + k4] = o;
    } else if (b < 2176) {                          // xB pad cols 176..191
        int idx = (b - 1920) * 256 + threadIdx.x;
        int r = idx >> 4, c = 176 + (idx & 15);
        xB[(size_t)r * 192 + c] = 0;
    } else if (b < 2180) {                          // biases
        int idx = (b - 2176) * 256 + threadIdx.x;
        if (idx < 704)
            bias1[idx] = (idx < 88) ? bfr[idx] : (idx < 216 ? bao[idx - 88] : 0.f);
        else if (idx < 960) {
            int n = idx - 704;
            bias2[n] = (n < 128) ? bac[n] : 0.f;
        }
    } else {                                        // sv sums
        int wid = threadIdx.x >> 6, lane = threadIdx.x & 63;
        const float* vp = (wid < 2) ? vo : vc;
        float val = vp[(wid & 1) * 64 + lane];
#pragma unroll
        for (int m = 32; m; m >>= 1) val += __shfl_xor(val, m, 64);
        if (lane == 0) red[wid] = val;
        __syncthreads();
        if (threadIdx.x == 0) {
            sv[0] = red[0] + red[1];
            sv[1] = red[2] + red[3];
        }
    }
}

// ---------------------------------------------------------------------------
// MFMA bf16 GEMM, no LDS; wave tile 16m x 64n, block 64m x 64n (4 waves).
// XCD swizzle: e=flat&7 -> rows [512e,512e+512) on XCD e (RTS=3).
// MODE 0 (gemm1) epilogue by column n:
//   n<88: feat fp32 + xB bf16 | 88..216: EHo=exp(2v) fp32 | 216..344: EPo bf16
//   344..472: EPc bf16 (both exp'd) | 472..560: Rb bf16 | 560..648: Qb bf16
// MODE 1 (gemm2): C2 fp32; n<128 -> exp(2v) (EH_c), else plain (linx).
// ---------------------------------------------------------------------------
template<int KITER, int RTS, int MODE>
__global__ __launch_bounds__(256) void gemm_mfma(
    const ushort_t* __restrict__ Ab, int lka,
    const ushort_t* __restrict__ Bb,
    const float* __restrict__ bias, int Nc,
    float* __restrict__ f0, ushort_t* __restrict__ u0,
    float* __restrict__ f1, ushort_t* __restrict__ u1,
    ushort_t* __restrict__ u2, ushort_t* __restrict__ u3,
    ushort_t* __restrict__ u4)
{
    const int tid = threadIdx.x;
    const int wv = tid >> 6, ln = tid & 63;
    const int l15 = ln & 15, qd = ln >> 4;
    const int flat = blockIdx.y * gridDim.x + blockIdx.x;
    const int e = flat & 7, kf = flat >> 3;
    const int rb = (e * (1 << RTS) + (kf & ((1 << RTS) - 1))) * 64;
    const int cb = (kf >> RTS) * 64;
    const int lkb = KITER * 32;

    const ushort_t* ap = Ab + (size_t)(rb + wv * 16 + l15) * lka + qd * 8;
    const ushort_t* bp[4];
#pragma unroll
    for (int nt = 0; nt < 4; nt++)
        bp[nt] = Bb + (size_t)(cb + nt * 16 + l15) * lkb + qd * 8;

    f32x4 acc[4];
#pragma unroll
    for (int nt = 0; nt < 4; nt++) acc[nt] = (f32x4){0.f, 0.f, 0.f, 0.f};

    bf16x8 af = *(const bf16x8*)ap, bfv[4];
#pragma unroll
    for (int nt = 0; nt < 4; nt++) bfv[nt] = *(const bf16x8*)bp[nt];

    for (int it = 0; it < KITER; it++) {
        bf16x8 an, bn[4];
        const int nk = (it + 1 < KITER) ? (it + 1) * 32 : 0;
        an = *(const bf16x8*)(ap + nk);
#pragma unroll
        for (int nt = 0; nt < 4; nt++) bn[nt] = *(const bf16x8*)(bp[nt] + nk);
#pragma unroll
        for (int nt = 0; nt < 4; nt++)
            acc[nt] = __builtin_amdgcn_mfma_f32_16x16x32_bf16(
                af, bfv[nt], acc[nt], 0, 0, 0);
        af = an;
#pragma unroll
        for (int nt = 0; nt < 4; nt++) bfv[nt] = bn[nt];
    }

    const int mbase = rb + wv * 16 + qd * 4;
#pragma unroll
    for (int nt = 0; nt < 4; nt++) {
        const int n = cb + nt * 16 + l15;
        if (n < Nc) {
            const float bn = bias[n];
#pragma unroll
            for (int r = 0; r < 4; r++) {
                const int m = mbase + r;
                float val = acc[nt][r] + bn;
                if (MODE == 0) {
                    if (n < 88) {
                        f0[(size_t)m * 88 + n] = val;            // feat
                        u0[(size_t)m * 192 + n] = f2bf(val);     // xB
                    } else if (n < 216) {
                        f1[(size_t)m * 128 + (n - 88)] = __expf(val + val);
                    } else if (n < 344) {
                        u1[(size_t)m * 128 + (n - 216)] = f2bf(__expf(val + val));
                    } else if (n < 472) {
                        u2[(size_t)m * 128 + (n - 344)] = f2bf(__expf(val + val));
                    } else if (n < 560) {
                        u3[(size_t)m * 96 + (n - 472)] = f2bf(val);
                    } else {
                        u4[(size_t)m * 96 + (n - 560)] = f2bf(val);
                    }
                } else {
                    f0[(size_t)m * 216 + n] = (n < 128) ? __expf(val + val) : val;
                }
            }
        }
    }
}

// ---------------------------------------------------------------------------
// Attention v9: TWO waves per position (d split in halves), 4 positions per
// 512-thread block -> grid 1024 blocks, 4 blocks/CU, 32 waves/CU (full occ).
// EP bf16 in LDS, row stride 132 ushorts = 66 words, gcd(66,32)=2 ->
// conflict-free b64 reads at lane-stride rows. Pad rows = bf16(1.0)=exp(0).
// R/Q bf16 in LDS (stride 96, pad rows = 0). EH fp32 + v fp32 via
// wave-uniform s_loads. Partial energies combined through LDS; softmax
// redundantly per half-wave; weighted sum split by feature half.
// ---------------------------------------------------------------------------
#define EPST 132
#define RST  96

__global__ __launch_bounds__(512) void attn_v9(
    const float* __restrict__ EH_all, int hs,
    const ushort_t* __restrict__ EPb,
    const ushort_t* __restrict__ Rb,
    const float* __restrict__ vvec, const float* __restrict__ svp,
    const float* __restrict__ pred_bias,
    const float* __restrict__ base, int bs,
    float* __restrict__ a_out, float* __restrict__ pred_out,
    ushort_t* __restrict__ xb)
{
    __shared__ ushort_t Pl[64 * EPST];   // 16,896 B
    __shared__ ushort_t Rl[64 * RST];    // 12,288 B
    __shared__ float Ep[4][2][64];       //  2,048 B

    const int tid = threadIdx.x;
    const int s0 = ((blockIdx.x & 7) * 128 + (blockIdx.x >> 3)) * 4;
    const int t0 = s0 & (TLEN - 1);

    // stage EP (64 rows x 128 bf16, uint2 chunks): pad rows = bf16(1.0)
    for (int i = tid; i < 64 * 32; i += 512) {
        int j = i >> 5, c = (i & 31) * 4;
        int tg = t0 + j - WSZ;
        uint2 v = {0x3f803f80u, 0x3f803f80u};
        if ((unsigned)tg < (unsigned)TLEN)
            v = *(const uint2*)&EPb[(size_t)(s0 - WSZ + j) * 128 + c];
        *(uint2*)&Pl[j * EPST + c] = v;
    }
    // stage R/Q (64 rows x 88 bf16, uint4 chunks): pad rows = 0
    for (int i = tid; i < 64 * 12; i += 512) {
        int j = i / 12, c = (i - j * 12) * 8;
        int tg = t0 + j - WSZ;
        uint4 v = {0u, 0u, 0u, 0u};
        if ((unsigned)tg < (unsigned)TLEN)
            v = *(const uint4*)&Rb[(size_t)(s0 - WSZ + j) * 96 + c];
        *(uint4*)&Rl[j * RST + c] = v;
    }
    __syncthreads();

    const int wv = tid >> 6;          // 0..7
    const int q  = wv >> 1;           // position within block
    const int hf = wv & 1;            // d-half (0: d<64, 1: d>=64)
    const int w  = tid & 63;          // lane = window index
    const int s  = s0 + q;
    const int su = __builtin_amdgcn_readfirstlane(s);
    const int row = q + ((w < WIN) ? w : 0);
    const ushort_t* pb = &Pl[row * EPST + hf * 64];
    const float* hrow = EH_all + (size_t)su * hs + hf * 64;  // uniform
    const float* vp0 = vvec + hf * 64;                       // uniform

    float accr = 0.f;
#pragma unroll
    for (int d4 = 0; d4 < 16; d4++) {
        uint2 pv = *(const uint2*)(pb + d4 * 4);       // b64, conflict-free
        const float* hp = hrow + d4 * 4;               // s_load
        const float* vp = vp0 + d4 * 4;                // s_load
        float p0 = __uint_as_float(pv.x << 16);
        float p1 = __uint_as_float(pv.x & 0xffff0000u);
        float p2 = __uint_as_float(pv.y << 16);
        float p3 = __uint_as_float(pv.y & 0xffff0000u);
        accr += vp[0] * __builtin_amdgcn_rcpf(__builtin_fmaf(hp[0], p0, 1.f));
        accr += vp[1] * __builtin_amdgcn_rcpf(__builtin_fmaf(hp[1], p1, 1.f));
        accr += vp[2] * __builtin_amdgcn_rcpf(__builtin_fmaf(hp[2], p2, 1.f));
        accr += vp[3] * __builtin_amdgcn_rcpf(__builtin_fmaf(hp[3], p3, 1.f));
    }
    Ep[q][hf][w] = accr;
    __syncthreads();

    float eng = svp[0] - 2.f * (Ep[q][0][w] + Ep[q][1][w]);
    if (w >= WIN) eng = -1e30f;

    // softmax over 61 windows (computed redundantly by both half-waves)
    float mx = eng;
#pragma unroll
    for (int m = 32; m; m >>= 1) mx = fmaxf(mx, __shfl_xor(mx, m, 64));
    float ex = __expf(eng - mx);
    float sm = ex;
#pragma unroll
    for (int m = 32; m; m >>= 1) sm += __shfl_xor(sm, m, 64);
    float a = ex * __builtin_amdgcn_rcpf(sm);
    if (hf == 0 && w < WIN) a_out[(size_t)s * WIN + w] = a;

    // weighted sum: this half-wave covers features [44*hf, 44*hf+44)
    if (w < 22) {
        const int f = 44 * hf + 2 * w;
        float acc0 = pred_bias[f], acc1 = pred_bias[f + 1];
        if (base) {
            acc0 += base[(size_t)s * bs + f];
            acc1 += base[(size_t)s * bs + f + 1];
        }
        const ushort_t* rr0 = &Rl[q * RST + f];
#pragma unroll
        for (int ww = 0; ww < WIN; ww++) {
            float aw = __uint_as_float(
                __builtin_amdgcn_readlane(__float_as_uint(a), ww));
            unsigned u = *(const unsigned*)(rr0 + ww * RST);
            acc0 += aw * __uint_as_float(u << 16);
            acc1 += aw * __uint_as_float(u & 0xffff0000u);
        }
        float p0 = sigmoid_f(acc0), p1 = sigmoid_f(acc1);
        *(float2*)&pred_out[(size_t)s * OUTF + f] = make_float2(p0, p1);
        if (xb) {
            ushort2 o; o.x = f2bf(p0); o.y = f2bf(p1);
            *(ushort2*)&xb[(size_t)s * 192 + 88 + f] = o;
        }
    }
}

// ---------------------------------------------------------------------------
extern "C" void kernel_launch(void* const* d_in, const int* in_sizes, int n_in,
                              void* d_out, int out_size, void* d_ws, size_t ws_size,
                              hipStream_t stream)
{
    const float* spec = (const float*)d_in[0];
    const float* Wf   = (const float*)d_in[1];
    const float* bf_  = (const float*)d_in[2];
    const float* Wao  = (const float*)d_in[3];
    const float* bao  = (const float*)d_in[4];
    const float* vo   = (const float*)d_in[5];
    const float* Wl1  = (const float*)d_in[6];
    const float* bl1  = (const float*)d_in[7];
    const float* Wac  = (const float*)d_in[8];
    const float* bac  = (const float*)d_in[9];
    const float* vc   = (const float*)d_in[10];
    const float* Wlc  = (const float*)d_in[11];
    const float* blc  = (const float*)d_in[12];

    float* out  = (float*)d_out;
    float* out0 = out;                 // frame_pred [BT,88]
    float* out1 = out + 360448;        // a_frame    [BT,61]
    float* out2 = out + 610304;        // onset_pred [BT,88]
    float* out3 = out + 970752;        // a_onset    [BT,61]
    float* out4 = out + 1220608;       // feat_pred  [BT,88]

    float* ws = (float*)d_ws;
    float*    sv    = ws;                          // 2 (pad 16)
    float*    bias1 = ws + 16;                     // 704
    float*    bias2 = ws + 720;                    // 256
    ushort_t* B1b   = (ushort_t*)(ws + 976);       // 704*256 u16
    ushort_t* B2b   = (ushort_t*)(ws + 91088);     // 256*192 u16
    ushort_t* specB = (ushort_t*)(ws + 115664);    // 4096*256 u16
    ushort_t* xB    = (ushort_t*)(ws + 639952);    // 4096*192 u16
    float*    EHo   = ws + 1033168;                // 4096*128 fp32
    ushort_t* EPo   = (ushort_t*)(ws + 1557456);   // 4096*128 u16
    ushort_t* EPc   = (ushort_t*)(ws + 1819600);   // 4096*128 u16
    ushort_t* Rb    = (ushort_t*)(ws + 2081744);   // 4096*96 u16
    ushort_t* Qb    = (ushort_t*)(ws + 2278352);   // 4096*96 u16
    float*    C2    = ws + 2474960;                // 4096*216 fp32
    (void)ws_size; (void)in_sizes; (void)n_in; (void)out_size;

    prep_kernel<<<PREP_BLOCKS, 256, 0, stream>>>(
        Wf, bf_, Wao, bao, Wl1, Wac, bac, Wlc, spec, vo, vc,
        B1b, B2b, specB, xB, bias1, bias2, sv);

    gemm_mfma<8, 3, 0><<<dim3(NP1 / 64, 64), 256, 0, stream>>>(
        specB, 256, B1b, bias1, NC1, out4, xB, EHo, EPo, EPc, Rb, Qb);

    attn_v9<<<BT / 4, 512, 0, stream>>>(
        EHo, 128, EPo, Rb, vo, sv, bl1, nullptr, 0, out3, out2, xB);

    gemm_mfma<6, 3, 1><<<dim3(4, 64), 256, 0, stream>>>(
        xB, 192, B2b, bias2, NC2, C2, nullptr, nullptr, nullptr,
        nullptr, nullptr, nullptr);

    attn_v9<<<BT / 4, 512, 0, stream>>>(
        C2, 216, EPc, Qb, vc, sv + 1, blc, C2 + 128, 216, out1, out0, nullptr);
}

// Round 11
// 134.442 us; speedup vs baseline: 1.0478x; 1.0478x over previous
//
#include <hip/hip_runtime.h>

#define NBINS 229
#define OUTF  88
#define MODEL 128
#define WSZ   30
#define WIN   61
#define TLEN  1024
#define BT    4096

#define NC1 648      // gemm1 real cols
#define NP1 704      // gemm1 padded cols (11*64)
#define KP1 256      // gemm1 padded K (8*32); real 229
#define NC2 216      // gemm2 real cols
#define KP2 192      // gemm2 padded K (6*32); real 176

typedef short bf16x8 __attribute__((ext_vector_type(8)));
typedef float f32x4 __attribute__((ext_vector_type(4)));
typedef unsigned short ushort_t;

__device__ __forceinline__ float sigmoid_f(float x) {
    return __builtin_amdgcn_rcpf(1.f + __expf(-x));
}
__device__ __forceinline__ ushort_t f2bf(float f) {
    unsigned u = __float_as_uint(f);
    return (ushort_t)((u + 0x7fffu + ((u >> 16) & 1u)) >> 16);
}

// ---------------------------------------------------------------------------
// prep: build bf16 GEMM operands + fp32 biases + sv sums + xB k-pad zeros.
// (identical to R9)
// ---------------------------------------------------------------------------
#define PREP_BLOCKS 2181

__global__ __launch_bounds__(256) void prep_kernel(
    const float* __restrict__ Wf,  const float* __restrict__ bfr,
    const float* __restrict__ Wao, const float* __restrict__ bao,
    const float* __restrict__ Wl1,
    const float* __restrict__ Wac, const float* __restrict__ bac,
    const float* __restrict__ Wlc,
    const float* __restrict__ spec,
    const float* __restrict__ vo, const float* __restrict__ vc,
    ushort_t* __restrict__ B1b, ushort_t* __restrict__ B2b,
    ushort_t* __restrict__ specB, ushort_t* __restrict__ xB,
    float* __restrict__ bias1, float* __restrict__ bias2,
    float* __restrict__ sv)
{
    __shared__ float red[4];
    const int b = blockIdx.x;
    if (b < 704) {                                  // B1b
        int idx = b * 256 + threadIdx.x;
        int n = idx >> 8, k = idx & 255;
        float v = 0.f;
        if (k < NBINS && n < NC1) {
            if (n < 88)       v = Wf[k * 88 + n];
            else if (n < 216) v = Wao[k * MODEL + (n - 88)];
            else if (n < 344) v = Wao[(k + NBINS) * MODEL + (n - 216)];
            else if (n < 472) v = Wac[(k + 176) * MODEL + (n - 344)];
            else if (n < 560) v = Wl1[k * 88 + (n - 472)];
            else              v = Wlc[(k + 176) * 88 + (n - 560)];
        }
        B1b[idx] = f2bf(v);
    } else if (b < 896) {                           // B2b
        int idx = (b - 704) * 256 + threadIdx.x;
        int n = idx / 192, k = idx - n * 192;
        float v = 0.f;
        if (k < 176 && n < NC2)
            v = (n < 128) ? Wac[k * MODEL + n] : Wlc[k * 88 + (n - 128)];
        B2b[idx] = f2bf(v);
    } else if (b < 1920) {                          // specB, 4 elems/thread
        int idx = (b - 896) * 256 + threadIdx.x;
        int r = idx >> 6, k4 = (idx & 63) * 4;
        const float* sp = spec + (size_t)r * NBINS;
        ushort4 o;
        o.x = (k4 + 0 < NBINS) ? f2bf(sp[k4 + 0]) : (ushort_t)0;
        o.y = (k4 + 1 < NBINS) ? f2bf(sp[k4 + 1]) : (ushort_t)0;
        o.z = (k4 + 2 < NBINS) ? f2bf(sp[k4 + 2]) : (ushort_t)0;
        o.w = (k4 + 3 < NBINS) ? f2bf(sp[k4 + 3]) : (ushort_t)0;
        *(ushort4*)&specB[(size_t)r * 256 + k4] = o;
    } else if (b < 2176) {                          // xB pad cols 176..191
        int idx = (b - 1920) * 256 + threadIdx.x;
        int r = idx >> 4, c = 176 + (idx & 15);
        xB[(size_t)r * 192 + c] = 0;
    } else if (b < 2180) {                          // biases
        int idx = (b - 2176) * 256 + threadIdx.x;
        if (idx < 704)
            bias1[idx] = (idx < 88) ? bfr[idx] : (idx < 216 ? bao[idx - 88] : 0.f);
        else if (idx < 960) {
            int n = idx - 704;
            bias2[n] = (n < 128) ? bac[n] : 0.f;
        }
    } else {                                        // sv sums
        int wid = threadIdx.x >> 6, lane = threadIdx.x & 63;
        const float* vp = (wid < 2) ? vo : vc;
        float val = vp[(wid & 1) * 64 + lane];
#pragma unroll
        for (int m = 32; m; m >>= 1) val += __shfl_xor(val, m, 64);
        if (lane == 0) red[wid] = val;
        __syncthreads();
        if (threadIdx.x == 0) {
            sv[0] = red[0] + red[1];
            sv[1] = red[2] + red[3];
        }
    }
}

// ---------------------------------------------------------------------------
// MFMA bf16 GEMM (identical to R9).
// ---------------------------------------------------------------------------
template<int KITER, int RTS, int MODE>
__global__ __launch_bounds__(256) void gemm_mfma(
    const ushort_t* __restrict__ Ab, int lka,
    const ushort_t* __restrict__ Bb,
    const float* __restrict__ bias, int Nc,
    float* __restrict__ f0, ushort_t* __restrict__ u0,
    float* __restrict__ f1, ushort_t* __restrict__ u1,
    ushort_t* __restrict__ u2, ushort_t* __restrict__ u3,
    ushort_t* __restrict__ u4)
{
    const int tid = threadIdx.x;
    const int wv = tid >> 6, ln = tid & 63;
    const int l15 = ln & 15, qd = ln >> 4;
    const int flat = blockIdx.y * gridDim.x + blockIdx.x;
    const int e = flat & 7, kf = flat >> 3;
    const int rb = (e * (1 << RTS) + (kf & ((1 << RTS) - 1))) * 64;
    const int cb = (kf >> RTS) * 64;
    const int lkb = KITER * 32;

    const ushort_t* ap = Ab + (size_t)(rb + wv * 16 + l15) * lka + qd * 8;
    const ushort_t* bp[4];
#pragma unroll
    for (int nt = 0; nt < 4; nt++)
        bp[nt] = Bb + (size_t)(cb + nt * 16 + l15) * lkb + qd * 8;

    f32x4 acc[4];
#pragma unroll
    for (int nt = 0; nt < 4; nt++) acc[nt] = (f32x4){0.f, 0.f, 0.f, 0.f};

    bf16x8 af = *(const bf16x8*)ap, bfv[4];
#pragma unroll
    for (int nt = 0; nt < 4; nt++) bfv[nt] = *(const bf16x8*)bp[nt];

    for (int it = 0; it < KITER; it++) {
        bf16x8 an, bn[4];
        const int nk = (it + 1 < KITER) ? (it + 1) * 32 : 0;
        an = *(const bf16x8*)(ap + nk);
#pragma unroll
        for (int nt = 0; nt < 4; nt++) bn[nt] = *(const bf16x8*)(bp[nt] + nk);
#pragma unroll
        for (int nt = 0; nt < 4; nt++)
            acc[nt] = __builtin_amdgcn_mfma_f32_16x16x32_bf16(
                af, bfv[nt], acc[nt], 0, 0, 0);
        af = an;
#pragma unroll
        for (int nt = 0; nt < 4; nt++) bfv[nt] = bn[nt];
    }

    const int mbase = rb + wv * 16 + qd * 4;
#pragma unroll
    for (int nt = 0; nt < 4; nt++) {
        const int n = cb + nt * 16 + l15;
        if (n < Nc) {
            const float bn = bias[n];
#pragma unroll
            for (int r = 0; r < 4; r++) {
                const int m = mbase + r;
                float val = acc[nt][r] + bn;
                if (MODE == 0) {
                    if (n < 88) {
                        f0[(size_t)m * 88 + n] = val;            // feat
                        u0[(size_t)m * 192 + n] = f2bf(val);     // xB
                    } else if (n < 216) {
                        f1[(size_t)m * 128 + (n - 88)] = __expf(val + val);
                    } else if (n < 344) {
                        u1[(size_t)m * 128 + (n - 216)] = f2bf(__expf(val + val));
                    } else if (n < 472) {
                        u2[(size_t)m * 128 + (n - 344)] = f2bf(__expf(val + val));
                    } else if (n < 560) {
                        u3[(size_t)m * 96 + (n - 472)] = f2bf(val);
                    } else {
                        u4[(size_t)m * 96 + (n - 560)] = f2bf(val);
                    }
                } else {
                    f0[(size_t)m * 216 + n] = (n < 128) ? __expf(val + val) : val;
                }
            }
        }
    }
}

// ---------------------------------------------------------------------------
// Attention v10 = R9's v8 structure (8 pos/block, 1 wave/pos, 512 blocks)
// with: (a) EP row stride 132 ushorts (66 words ≡ 2 mod 32: near-benign
// aliasing vs 136's 8-way), uint2 energy reads (8B-aligned at all rows);
// (b) 4 independent energy accumulators (break the 128-deep fma chain);
// (c) 4 accumulators in the weighted sum (even/odd window phases).
// ---------------------------------------------------------------------------
#define EPST 132
#define RST  96

__global__ __launch_bounds__(512) void attn_v10(
    const float* __restrict__ EH_all, int hs,
    const ushort_t* __restrict__ EPb,
    const ushort_t* __restrict__ Rb,
    const float* __restrict__ vvec, const float* __restrict__ svp,
    const float* __restrict__ pred_bias,
    const float* __restrict__ base, int bs,
    float* __restrict__ a_out, float* __restrict__ pred_out,
    ushort_t* __restrict__ xb)
{
    __shared__ ushort_t Pl[68 * EPST];   // 17,952 B
    __shared__ ushort_t Rl[68 * RST];    // 13,056 B

    const int tid = threadIdx.x;
    const int s0 = ((blockIdx.x & 7) * 64 + (blockIdx.x >> 3)) * 8;
    const int t0 = s0 & (TLEN - 1);

    // stage EP (68 rows x 128 bf16, uint2 chunks): pad rows = bf16(1.0)
    for (int i = tid; i < 68 * 32; i += 512) {
        int j = i >> 5, c = (i & 31) * 4;
        int tg = t0 + j - WSZ;
        uint2 v = {0x3f803f80u, 0x3f803f80u};
        if ((unsigned)tg < (unsigned)TLEN)
            v = *(const uint2*)&EPb[(size_t)(s0 - WSZ + j) * 128 + c];
        *(uint2*)&Pl[j * EPST + c] = v;
    }
    // stage R/Q (68 rows x 88 bf16, uint4 chunks): pad rows = 0
    for (int i = tid; i < 68 * 12; i += 512) {
        int j = i / 12, c = (i - j * 12) * 8;
        int tg = t0 + j - WSZ;
        uint4 v = {0u, 0u, 0u, 0u};
        if ((unsigned)tg < (unsigned)TLEN)
            v = *(const uint4*)&Rb[(size_t)(s0 - WSZ + j) * 96 + c];
        *(uint4*)&Rl[j * RST + c] = v;
    }
    __syncthreads();

    const int q = tid >> 6;
    const int w = tid & 63;
    const int s = s0 + q;
    const int su = __builtin_amdgcn_readfirstlane(s);
    const int row = q + ((w < WIN) ? w : 0);
    const ushort_t* pb = &Pl[row * EPST];
    const float* hrow = EH_all + (size_t)su * hs;   // uniform -> s_load
    const float sv = svp[0];

    float ac0 = 0.f, ac1 = 0.f, ac2 = 0.f, ac3 = 0.f;
#pragma unroll
    for (int d4 = 0; d4 < 32; d4++) {
        uint2 pv = *(const uint2*)(pb + d4 * 4);
        const float* hp = hrow + d4 * 4;
        const float* vp = vvec + d4 * 4;
        float p0 = __uint_as_float(pv.x << 16);
        float p1 = __uint_as_float(pv.x & 0xffff0000u);
        float p2 = __uint_as_float(pv.y << 16);
        float p3 = __uint_as_float(pv.y & 0xffff0000u);
        ac0 += vp[0] * __builtin_amdgcn_rcpf(__builtin_fmaf(hp[0], p0, 1.f));
        ac1 += vp[1] * __builtin_amdgcn_rcpf(__builtin_fmaf(hp[1], p1, 1.f));
        ac2 += vp[2] * __builtin_amdgcn_rcpf(__builtin_fmaf(hp[2], p2, 1.f));
        ac3 += vp[3] * __builtin_amdgcn_rcpf(__builtin_fmaf(hp[3], p3, 1.f));
    }
    float eng = sv - 2.f * ((ac0 + ac1) + (ac2 + ac3));
    if (w >= WIN) eng = -1e30f;

    float mx = eng;
#pragma unroll
    for (int m = 32; m; m >>= 1) mx = fmaxf(mx, __shfl_xor(mx, m, 64));
    float ex = __expf(eng - mx);
    float sm = ex;
#pragma unroll
    for (int m = 32; m; m >>= 1) sm += __shfl_xor(sm, m, 64);
    float a = ex * __builtin_amdgcn_rcpf(sm);
    if (w < WIN) a_out[(size_t)s * WIN + w] = a;

    if (w < 44) {
        const int f = 2 * w;
        float acc0 = pred_bias[f], acc1 = pred_bias[f + 1];
        float acc2 = 0.f, acc3 = 0.f;
        if (base) {
            acc0 += base[(size_t)s * bs + f];
            acc1 += base[(size_t)s * bs + f + 1];
        }
        const ushort_t* rr0 = &Rl[q * RST + f];
#pragma unroll
        for (int ww = 0; ww < 60; ww += 2) {
            float aw0 = __uint_as_float(
                __builtin_amdgcn_readlane(__float_as_uint(a), ww));
            float aw1 = __uint_as_float(
                __builtin_amdgcn_readlane(__float_as_uint(a), ww + 1));
            unsigned u0 = *(const unsigned*)(rr0 + ww * RST);
            unsigned u1 = *(const unsigned*)(rr0 + (ww + 1) * RST);
            acc0 += aw0 * __uint_as_float(u0 << 16);
            acc1 += aw0 * __uint_as_float(u0 & 0xffff0000u);
            acc2 += aw1 * __uint_as_float(u1 << 16);
            acc3 += aw1 * __uint_as_float(u1 & 0xffff0000u);
        }
        {
            float aw = __uint_as_float(
                __builtin_amdgcn_readlane(__float_as_uint(a), 60));
            unsigned u = *(const unsigned*)(rr0 + 60 * RST);
            acc0 += aw * __uint_as_float(u << 16);
            acc1 += aw * __uint_as_float(u & 0xffff0000u);
        }
        float p0 = sigmoid_f(acc0 + acc2), p1 = sigmoid_f(acc1 + acc3);
        *(float2*)&pred_out[(size_t)s * OUTF + f] = make_float2(p0, p1);
        if (xb) {
            ushort2 o; o.x = f2bf(p0); o.y = f2bf(p1);
            *(ushort2*)&xb[(size_t)s * 192 + 88 + f] = o;
        }
    }
}

// ---------------------------------------------------------------------------
extern "C" void kernel_launch(void* const* d_in, const int* in_sizes, int n_in,
                              void* d_out, int out_size, void* d_ws, size_t ws_size,
                              hipStream_t stream)
{
    const float* spec = (const float*)d_in[0];
    const float* Wf   = (const float*)d_in[1];
    const float* bf_  = (const float*)d_in[2];
    const float* Wao  = (const float*)d_in[3];
    const float* bao  = (const float*)d_in[4];
    const float* vo   = (const float*)d_in[5];
    const float* Wl1  = (const float*)d_in[6];
    const float* bl1  = (const float*)d_in[7];
    const float* Wac  = (const float*)d_in[8];
    const float* bac  = (const float*)d_in[9];
    const float* vc   = (const float*)d_in[10];
    const float* Wlc  = (const float*)d_in[11];
    const float* blc  = (const float*)d_in[12];

    float* out  = (float*)d_out;
    float* out0 = out;                 // frame_pred [BT,88]
    float* out1 = out + 360448;        // a_frame    [BT,61]
    float* out2 = out + 610304;        // onset_pred [BT,88]
    float* out3 = out + 970752;        // a_onset    [BT,61]
    float* out4 = out + 1220608;       // feat_pred  [BT,88]

    float* ws = (float*)d_ws;
    float*    sv    = ws;                          // 2 (pad 16)
    float*    bias1 = ws + 16;                     // 704
    float*    bias2 = ws + 720;                    // 256
    ushort_t* B1b   = (ushort_t*)(ws + 976);       // 704*256 u16
    ushort_t* B2b   = (ushort_t*)(ws + 91088);     // 256*192 u16
    ushort_t* specB = (ushort_t*)(ws + 115664);    // 4096*256 u16
    ushort_t* xB    = (ushort_t*)(ws + 639952);    // 4096*192 u16
    float*    EHo   = ws + 1033168;                // 4096*128 fp32
    ushort_t* EPo   = (ushort_t*)(ws + 1557456);   // 4096*128 u16
    ushort_t* EPc   = (ushort_t*)(ws + 1819600);   // 4096*128 u16
    ushort_t* Rb    = (ushort_t*)(ws + 2081744);   // 4096*96 u16
    ushort_t* Qb    = (ushort_t*)(ws + 2278352);   // 4096*96 u16
    float*    C2    = ws + 2474960;                // 4096*216 fp32
    (void)ws_size; (void)in_sizes; (void)n_in; (void)out_size;

    prep_kernel<<<PREP_BLOCKS, 256, 0, stream>>>(
        Wf, bf_, Wao, bao, Wl1, Wac, bac, Wlc, spec, vo, vc,
        B1b, B2b, specB, xB, bias1, bias2, sv);

    gemm_mfma<8, 3, 0><<<dim3(NP1 / 64, 64), 256, 0, stream>>>(
        specB, 256, B1b, bias1, NC1, out4, xB, EHo, EPo, EPc, Rb, Qb);

    attn_v10<<<BT / 8, 512, 0, stream>>>(
        EHo, 128, EPo, Rb, vo, sv, bl1, nullptr, 0, out3, out2, xB);

    gemm_mfma<6, 3, 1><<<dim3(4, 64), 256, 0, stream>>>(
        xB, 192, B2b, bias2, NC2, C2, nullptr, nullptr, nullptr,
        nullptr, nullptr, nullptr);

    attn_v10<<<BT / 8, 512, 0, stream>>>(
        C2, 216, EPc, Qb, vc, sv + 1, blc, C2 + 128, 216, out1, out0, nullptr);
}

// Round 12
// 134.336 us; speedup vs baseline: 1.0486x; 1.0008x over previous
//
#include <hip/hip_runtime.h>

#define NBINS 229
#define OUTF  88
#define MODEL 128
#define WSZ   30
#define WIN   61
#define TLEN  1024
#define BT    4096

#define NC1 648      // gemm1 real cols
#define NP1 704      // gemm1 padded cols (11*64)
#define KP1 256      // gemm1 padded K (8*32); real 229
#define NC2 216      // gemm2 real cols
#define KP2 192      // gemm2 padded K (6*32); real 176

typedef short bf16x8 __attribute__((ext_vector_type(8)));
typedef float f32x4 __attribute__((ext_vector_type(4)));
typedef unsigned short ushort_t;

__device__ __forceinline__ float sigmoid_f(float x) {
    return __builtin_amdgcn_rcpf(1.f + __expf(-x));
}
__device__ __forceinline__ ushort_t f2bf(float f) {
    unsigned u = __float_as_uint(f);
    return (ushort_t)((u + 0x7fffu + ((u >> 16) & 1u)) >> 16);
}

// ---------------------------------------------------------------------------
// prep: build bf16 GEMM operands + fp32 biases + sv sums + xB k-pad zeros.
// (identical to R9/R11)
// ---------------------------------------------------------------------------
#define PREP_BLOCKS 2181

__global__ __launch_bounds__(256) void prep_kernel(
    const float* __restrict__ Wf,  const float* __restrict__ bfr,
    const float* __restrict__ Wao, const float* __restrict__ bao,
    const float* __restrict__ Wl1,
    const float* __restrict__ Wac, const float* __restrict__ bac,
    const float* __restrict__ Wlc,
    const float* __restrict__ spec,
    const float* __restrict__ vo, const float* __restrict__ vc,
    ushort_t* __restrict__ B1b, ushort_t* __restrict__ B2b,
    ushort_t* __restrict__ specB, ushort_t* __restrict__ xB,
    float* __restrict__ bias1, float* __restrict__ bias2,
    float* __restrict__ sv)
{
    __shared__ float red[4];
    const int b = blockIdx.x;
    if (b < 704) {                                  // B1b
        int idx = b * 256 + threadIdx.x;
        int n = idx >> 8, k = idx & 255;
        float v = 0.f;
        if (k < NBINS && n < NC1) {
            if (n < 88)       v = Wf[k * 88 + n];
            else if (n < 216) v = Wao[k * MODEL + (n - 88)];
            else if (n < 344) v = Wao[(k + NBINS) * MODEL + (n - 216)];
            else if (n < 472) v = Wac[(k + 176) * MODEL + (n - 344)];
            else if (n < 560) v = Wl1[k * 88 + (n - 472)];
            else              v = Wlc[(k + 176) * 88 + (n - 560)];
        }
        B1b[idx] = f2bf(v);
    } else if (b < 896) {                           // B2b
        int idx = (b - 704) * 256 + threadIdx.x;
        int n = idx / 192, k = idx - n * 192;
        float v = 0.f;
        if (k < 176 && n < NC2)
            v = (n < 128) ? Wac[k * MODEL + n] : Wlc[k * 88 + (n - 128)];
        B2b[idx] = f2bf(v);
    } else if (b < 1920) {                          // specB, 4 elems/thread
        int idx = (b - 896) * 256 + threadIdx.x;
        int r = idx >> 6, k4 = (idx & 63) * 4;
        const float* sp = spec + (size_t)r * NBINS;
        ushort4 o;
        o.x = (k4 + 0 < NBINS) ? f2bf(sp[k4 + 0]) : (ushort_t)0;
        o.y = (k4 + 1 < NBINS) ? f2bf(sp[k4 + 1]) : (ushort_t)0;
        o.z = (k4 + 2 < NBINS) ? f2bf(sp[k4 + 2]) : (ushort_t)0;
        o.w = (k4 + 3 < NBINS) ? f2bf(sp[k4 + 3]) : (ushort_t)0;
        *(ushort4*)&specB[(size_t)r * 256 + k4] = o;
    } else if (b < 2176) {                          // xB pad cols 176..191
        int idx = (b - 1920) * 256 + threadIdx.x;
        int r = idx >> 4, c = 176 + (idx & 15);
        xB[(size_t)r * 192 + c] = 0;
    } else if (b < 2180) {                          // biases
        int idx = (b - 2176) * 256 + threadIdx.x;
        if (idx < 704)
            bias1[idx] = (idx < 88) ? bfr[idx] : (idx < 216 ? bao[idx - 88] : 0.f);
        else if (idx < 960) {
            int n = idx - 704;
            bias2[n] = (n < 128) ? bac[n] : 0.f;
        }
    } else {                                        // sv sums
        int wid = threadIdx.x >> 6, lane = threadIdx.x & 63;
        const float* vp = (wid < 2) ? vo : vc;
        float val = vp[(wid & 1) * 64 + lane];
#pragma unroll
        for (int m = 32; m; m >>= 1) val += __shfl_xor(val, m, 64);
        if (lane == 0) red[wid] = val;
        __syncthreads();
        if (threadIdx.x == 0) {
            sv[0] = red[0] + red[1];
            sv[1] = red[2] + red[3];
        }
    }
}

// ---------------------------------------------------------------------------
// MFMA bf16 GEMM (identical to R9/R11).
// ---------------------------------------------------------------------------
template<int KITER, int RTS, int MODE>
__global__ __launch_bounds__(256) void gemm_mfma(
    const ushort_t* __restrict__ Ab, int lka,
    const ushort_t* __restrict__ Bb,
    const float* __restrict__ bias, int Nc,
    float* __restrict__ f0, ushort_t* __restrict__ u0,
    float* __restrict__ f1, ushort_t* __restrict__ u1,
    ushort_t* __restrict__ u2, ushort_t* __restrict__ u3,
    ushort_t* __restrict__ u4)
{
    const int tid = threadIdx.x;
    const int wv = tid >> 6, ln = tid & 63;
    const int l15 = ln & 15, qd = ln >> 4;
    const int flat = blockIdx.y * gridDim.x + blockIdx.x;
    const int e = flat & 7, kf = flat >> 3;
    const int rb = (e * (1 << RTS) + (kf & ((1 << RTS) - 1))) * 64;
    const int cb = (kf >> RTS) * 64;
    const int lkb = KITER * 32;

    const ushort_t* ap = Ab + (size_t)(rb + wv * 16 + l15) * lka + qd * 8;
    const ushort_t* bp[4];
#pragma unroll
    for (int nt = 0; nt < 4; nt++)
        bp[nt] = Bb + (size_t)(cb + nt * 16 + l15) * lkb + qd * 8;

    f32x4 acc[4];
#pragma unroll
    for (int nt = 0; nt < 4; nt++) acc[nt] = (f32x4){0.f, 0.f, 0.f, 0.f};

    bf16x8 af = *(const bf16x8*)ap, bfv[4];
#pragma unroll
    for (int nt = 0; nt < 4; nt++) bfv[nt] = *(const bf16x8*)bp[nt];

    for (int it = 0; it < KITER; it++) {
        bf16x8 an, bn[4];
        const int nk = (it + 1 < KITER) ? (it + 1) * 32 : 0;
        an = *(const bf16x8*)(ap + nk);
#pragma unroll
        for (int nt = 0; nt < 4; nt++) bn[nt] = *(const bf16x8*)(bp[nt] + nk);
#pragma unroll
        for (int nt = 0; nt < 4; nt++)
            acc[nt] = __builtin_amdgcn_mfma_f32_16x16x32_bf16(
                af, bfv[nt], acc[nt], 0, 0, 0);
        af = an;
#pragma unroll
        for (int nt = 0; nt < 4; nt++) bfv[nt] = bn[nt];
    }

    const int mbase = rb + wv * 16 + qd * 4;
#pragma unroll
    for (int nt = 0; nt < 4; nt++) {
        const int n = cb + nt * 16 + l15;
        if (n < Nc) {
            const float bn = bias[n];
#pragma unroll
            for (int r = 0; r < 4; r++) {
                const int m = mbase + r;
                float val = acc[nt][r] + bn;
                if (MODE == 0) {
                    if (n < 88) {
                        f0[(size_t)m * 88 + n] = val;            // feat
                        u0[(size_t)m * 192 + n] = f2bf(val);     // xB
                    } else if (n < 216) {
                        f1[(size_t)m * 128 + (n - 88)] = __expf(val + val);
                    } else if (n < 344) {
                        u1[(size_t)m * 128 + (n - 216)] = f2bf(__expf(val + val));
                    } else if (n < 472) {
                        u2[(size_t)m * 128 + (n - 344)] = f2bf(__expf(val + val));
                    } else if (n < 560) {
                        u3[(size_t)m * 96 + (n - 472)] = f2bf(val);
                    } else {
                        u4[(size_t)m * 96 + (n - 560)] = f2bf(val);
                    }
                } else {
                    f0[(size_t)m * 216 + n] = (n < 128) ? __expf(val + val) : val;
                }
            }
        }
    }
}

// ---------------------------------------------------------------------------
// Attention v11 = v10 with EH moved from the scalar-load path into LDS.
// EH rows are unique per wave -> scalar-L1 misses serialized the energy
// loop (SGPR budget forces chunked s_load + waitcnt). Now EH is staged
// once per block (8 x 128 fp32 = 4 KB) and read as ds_read_b128
// BROADCASTS (all lanes same address: conflict-free, pipelined).
// vvec stays s_load (shared across all blocks -> scalar-cache-hot).
// ---------------------------------------------------------------------------
#define EPST 132
#define RST  96

__global__ __launch_bounds__(512) void attn_v11(
    const float* __restrict__ EH_all, int hs,
    const ushort_t* __restrict__ EPb,
    const ushort_t* __restrict__ Rb,
    const float* __restrict__ vvec, const float* __restrict__ svp,
    const float* __restrict__ pred_bias,
    const float* __restrict__ base, int bs,
    float* __restrict__ a_out, float* __restrict__ pred_out,
    ushort_t* __restrict__ xb)
{
    __shared__ ushort_t Pl[68 * EPST];   // 17,952 B
    __shared__ ushort_t Rl[68 * RST];    // 13,056 B
    __shared__ float    EHl[8][128];     //  4,096 B

    const int tid = threadIdx.x;
    const int s0 = ((blockIdx.x & 7) * 64 + (blockIdx.x >> 3)) * 8;
    const int t0 = s0 & (TLEN - 1);

    // stage EH (8 rows x 128 fp32), float4 coalesced
    for (int i = tid; i < 8 * 32; i += 512) {
        int r = i >> 5, c4 = (i & 31) * 4;
        *(float4*)&EHl[r][c4] =
            *(const float4*)&EH_all[(size_t)(s0 + r) * hs + c4];
    }
    // stage EP (68 rows x 128 bf16, uint2 chunks): pad rows = bf16(1.0)
    for (int i = tid; i < 68 * 32; i += 512) {
        int j = i >> 5, c = (i & 31) * 4;
        int tg = t0 + j - WSZ;
        uint2 v = {0x3f803f80u, 0x3f803f80u};
        if ((unsigned)tg < (unsigned)TLEN)
            v = *(const uint2*)&EPb[(size_t)(s0 - WSZ + j) * 128 + c];
        *(uint2*)&Pl[j * EPST + c] = v;
    }
    // stage R/Q (68 rows x 88 bf16, uint4 chunks): pad rows = 0
    for (int i = tid; i < 68 * 12; i += 512) {
        int j = i / 12, c = (i - j * 12) * 8;
        int tg = t0 + j - WSZ;
        uint4 v = {0u, 0u, 0u, 0u};
        if ((unsigned)tg < (unsigned)TLEN)
            v = *(const uint4*)&Rb[(size_t)(s0 - WSZ + j) * 96 + c];
        *(uint4*)&Rl[j * RST + c] = v;
    }
    __syncthreads();

    const int q = tid >> 6;
    const int w = tid & 63;
    const int s = s0 + q;
    const int row = q + ((w < WIN) ? w : 0);
    const ushort_t* pb = &Pl[row * EPST];
    const float* ehrow = &EHl[q][0];                // LDS broadcast
    const float sv = svp[0];

    float ac0 = 0.f, ac1 = 0.f, ac2 = 0.f, ac3 = 0.f;
#pragma unroll
    for (int d4 = 0; d4 < 32; d4++) {
        uint2 pv = *(const uint2*)(pb + d4 * 4);            // per-lane b64
        float4 hh = *(const float4*)(ehrow + d4 * 4);       // b128 broadcast
        const float* vp = vvec + d4 * 4;                    // s_load (hot)
        float p0 = __uint_as_float(pv.x << 16);
        float p1 = __uint_as_float(pv.x & 0xffff0000u);
        float p2 = __uint_as_float(pv.y << 16);
        float p3 = __uint_as_float(pv.y & 0xffff0000u);
        ac0 += vp[0] * __builtin_amdgcn_rcpf(__builtin_fmaf(hh.x, p0, 1.f));
        ac1 += vp[1] * __builtin_amdgcn_rcpf(__builtin_fmaf(hh.y, p1, 1.f));
        ac2 += vp[2] * __builtin_amdgcn_rcpf(__builtin_fmaf(hh.z, p2, 1.f));
        ac3 += vp[3] * __builtin_amdgcn_rcpf(__builtin_fmaf(hh.w, p3, 1.f));
    }
    float eng = sv - 2.f * ((ac0 + ac1) + (ac2 + ac3));
    if (w >= WIN) eng = -1e30f;

    float mx = eng;
#pragma unroll
    for (int m = 32; m; m >>= 1) mx = fmaxf(mx, __shfl_xor(mx, m, 64));
    float ex = __expf(eng - mx);
    float sm = ex;
#pragma unroll
    for (int m = 32; m; m >>= 1) sm += __shfl_xor(sm, m, 64);
    float a = ex * __builtin_amdgcn_rcpf(sm);
    if (w < WIN) a_out[(size_t)s * WIN + w] = a;

    if (w < 44) {
        const int f = 2 * w;
        float acc0 = pred_bias[f], acc1 = pred_bias[f + 1];
        float acc2 = 0.f, acc3 = 0.f;
        if (base) {
            acc0 += base[(size_t)s * bs + f];
            acc1 += base[(size_t)s * bs + f + 1];
        }
        const ushort_t* rr0 = &Rl[q * RST + f];
#pragma unroll
        for (int ww = 0; ww < 60; ww += 2) {
            float aw0 = __uint_as_float(
                __builtin_amdgcn_readlane(__float_as_uint(a), ww));
            float aw1 = __uint_as_float(
                __builtin_amdgcn_readlane(__float_as_uint(a), ww + 1));
            unsigned u0 = *(const unsigned*)(rr0 + ww * RST);
            unsigned u1 = *(const unsigned*)(rr0 + (ww + 1) * RST);
            acc0 += aw0 * __uint_as_float(u0 << 16);
            acc1 += aw0 * __uint_as_float(u0 & 0xffff0000u);
            acc2 += aw1 * __uint_as_float(u1 << 16);
            acc3 += aw1 * __uint_as_float(u1 & 0xffff0000u);
        }
        {
            float aw = __uint_as_float(
                __builtin_amdgcn_readlane(__float_as_uint(a), 60));
            unsigned u = *(const unsigned*)(rr0 + 60 * RST);
            acc0 += aw * __uint_as_float(u << 16);
            acc1 += aw * __uint_as_float(u & 0xffff0000u);
        }
        float p0 = sigmoid_f(acc0 + acc2), p1 = sigmoid_f(acc1 + acc3);
        *(float2*)&pred_out[(size_t)s * OUTF + f] = make_float2(p0, p1);
        if (xb) {
            ushort2 o; o.x = f2bf(p0); o.y = f2bf(p1);
            *(ushort2*)&xb[(size_t)s * 192 + 88 + f] = o;
        }
    }
}

// ---------------------------------------------------------------------------
extern "C" void kernel_launch(void* const* d_in, const int* in_sizes, int n_in,
                              void* d_out, int out_size, void* d_ws, size_t ws_size,
                              hipStream_t stream)
{
    const float* spec = (const float*)d_in[0];
    const float* Wf   = (const float*)d_in[1];
    const float* bf_  = (const float*)d_in[2];
    const float* Wao  = (const float*)d_in[3];
    const float* bao  = (const float*)d_in[4];
    const float* vo   = (const float*)d_in[5];
    const float* Wl1  = (const float*)d_in[6];
    const float* bl1  = (const float*)d_in[7];
    const float* Wac  = (const float*)d_in[8];
    const float* bac  = (const float*)d_in[9];
    const float* vc   = (const float*)d_in[10];
    const float* Wlc  = (const float*)d_in[11];
    const float* blc  = (const float*)d_in[12];

    float* out  = (float*)d_out;
    float* out0 = out;                 // frame_pred [BT,88]
    float* out1 = out + 360448;        // a_frame    [BT,61]
    float* out2 = out + 610304;        // onset_pred [BT,88]
    float* out3 = out + 970752;        // a_onset    [BT,61]
    float* out4 = out + 1220608;       // feat_pred  [BT,88]

    float* ws = (float*)d_ws;
    float*    sv    = ws;                          // 2 (pad 16)
    float*    bias1 = ws + 16;                     // 704
    float*    bias2 = ws + 720;                    // 256
    ushort_t* B1b   = (ushort_t*)(ws + 976);       // 704*256 u16
    ushort_t* B2b   = (ushort_t*)(ws + 91088);     // 256*192 u16
    ushort_t* specB = (ushort_t*)(ws + 115664);    // 4096*256 u16
    ushort_t* xB    = (ushort_t*)(ws + 639952);    // 4096*192 u16
    float*    EHo   = ws + 1033168;                // 4096*128 fp32
    ushort_t* EPo   = (ushort_t*)(ws + 1557456);   // 4096*128 u16
    ushort_t* EPc   = (ushort_t*)(ws + 1819600);   // 4096*128 u16
    ushort_t* Rb    = (ushort_t*)(ws + 2081744);   // 4096*96 u16
    ushort_t* Qb    = (ushort_t*)(ws + 2278352);   // 4096*96 u16
    float*    C2    = ws + 2474960;                // 4096*216 fp32
    (void)ws_size; (void)in_sizes; (void)n_in; (void)out_size;

    prep_kernel<<<PREP_BLOCKS, 256, 0, stream>>>(
        Wf, bf_, Wao, bao, Wl1, Wac, bac, Wlc, spec, vo, vc,
        B1b, B2b, specB, xB, bias1, bias2, sv);

    gemm_mfma<8, 3, 0><<<dim3(NP1 / 64, 64), 256, 0, stream>>>(
        specB, 256, B1b, bias1, NC1, out4, xB, EHo, EPo, EPc, Rb, Qb);

    attn_v11<<<BT / 8, 512, 0, stream>>>(
        EHo, 128, EPo, Rb, vo, sv, bl1, nullptr, 0, out3, out2, xB);

    gemm_mfma<6, 3, 1><<<dim3(4, 64), 256, 0, stream>>>(
        xB, 192, B2b, bias2, NC2, C2, nullptr, nullptr, nullptr,
        nullptr, nullptr, nullptr);

    attn_v11<<<BT / 8, 512, 0, stream>>>(
        C2, 216, EPc, Qb, vc, sv + 1, blc, C2 + 128, 216, out1, out0, nullptr);
}